// Round 5
// baseline (55.610 us; speedup 1.0000x reference)
//
#include <hip/hip_runtime.h>
#include <math.h>

#define HKn 16
#define HVn 32
#define DDn 128
#define CCn 8192          // D*(2*HK+HV)
#define EPSN 1e-6f
#define QSCALE 0.08838834764831845f   // 1/sqrt(128)

typedef float vf4 __attribute__((ext_vector_type(4)));   // native vector for nontemporal builtins

// One block per (b, h_v). Fully fused single pass:
//   out[row] = sum_c S[row][c] * w[c] + beta*kq * v[row]
//   w[c] = eg*(q_n[c]*scale - beta*kq*k_n[c])
// State loads are nontemporal (pure 256MB stream, no reuse).
// First 2 row-chunks are loaded into registers BEFORE the phase-A sync to
// keep the memory pipe busy during the conv/exp chain.
__global__ __launch_bounds__(256) void fused_gdn_decode(
    const float* __restrict__ mixed_qkv,
    const float* __restrict__ a_in,
    const float* __restrict__ b_in,
    const float* __restrict__ conv_state,
    const float* __restrict__ ssm_state,
    const float* __restrict__ conv_weights,
    const float* __restrict__ dt_bias,
    const float* __restrict__ A_log,
    float* __restrict__ out)
{
    const int bh = blockIdx.x;     // b*HV + h
    const int b  = bh >> 5;
    const int h  = bh & 31;
    const int qh = h >> 1;         // rep = HV/HK = 2
    const int t  = threadIdx.x;

    __shared__ float wv[DDn];      // combined weight vector (cols)
    __shared__ float vb[DDn];      // silu'd v
    __shared__ float po[DDn];      // per-row dot results
    __shared__ float red[6];       // 2 waves x {sum q^2, sum k^2, sum q*k}

    const float* cs = conv_state + (size_t)b * 3 * CCn;
    const float* mq = mixed_qkv  + (size_t)b * CCn;

    // ---- early state loads (independent of phase A) ----
    const int colg = t & 15;
    const int rb   = t >> 4;           // 0..15
    const float* S = ssm_state + (size_t)bh * DDn * DDn;
    const float* Sr0 = S + (size_t)(0 * 16 + rb) * DDn + colg * 8;
    const float* Sr1 = S + (size_t)(1 * 16 + rb) * DDn + colg * 8;
    vf4 e00 = __builtin_nontemporal_load(reinterpret_cast<const vf4*>(Sr0));
    vf4 e01 = __builtin_nontemporal_load(reinterpret_cast<const vf4*>(Sr0 + 4));
    vf4 e10 = __builtin_nontemporal_load(reinterpret_cast<const vf4*>(Sr1));
    vf4 e11 = __builtin_nontemporal_load(reinterpret_cast<const vf4*>(Sr1 + 4));

    float xq = 0.f, xk = 0.f, bkq = 0.f;

    if (t < DDn) {
        // conv + silu for q-channel and k-channel
        const int cq = qh * DDn + t;
        const int ck = (HKn + qh) * DDn + t;
        float4 w = *reinterpret_cast<const float4*>(conv_weights + (size_t)cq * 4);
        float x = cs[cq] * w.x + cs[CCn + cq] * w.y + cs[2 * CCn + cq] * w.z + mq[cq] * w.w;
        xq = x / (1.f + __expf(-x));
        w = *reinterpret_cast<const float4*>(conv_weights + (size_t)ck * 4);
        x = cs[ck] * w.x + cs[CCn + ck] * w.y + cs[2 * CCn + ck] * w.z + mq[ck] * w.w;
        xk = x / (1.f + __expf(-x));

        float sqq = xq * xq, skk = xk * xk, sqk = xq * xk;
        #pragma unroll
        for (int m = 1; m <= 32; m <<= 1) {
            sqq += __shfl_xor(sqq, m);
            skk += __shfl_xor(skk, m);
            sqk += __shfl_xor(sqk, m);
        }
        if ((t & 63) == 0) {
            const int wv_ = t >> 6;
            red[wv_ * 3 + 0] = sqq;
            red[wv_ * 3 + 1] = skk;
            red[wv_ * 3 + 2] = sqk;
        }
    } else {
        // conv + silu for v-channel
        const int cv = (2 * HKn + h) * DDn + (t - DDn);
        float4 w = *reinterpret_cast<const float4*>(conv_weights + (size_t)cv * 4);
        float x = cs[cv] * w.x + cs[CCn + cv] * w.y + cs[2 * CCn + cv] * w.z + mq[cv] * w.w;
        vb[t - DDn] = x / (1.f + __expf(-x));
    }
    __syncthreads();

    if (t < DDn) {
        const float sqq = red[0] + red[3];
        const float skk = red[1] + red[4];
        const float sqk = red[2] + red[5];
        const float rq = rsqrtf(sqq + EPSN);
        const float rk = rsqrtf(skk + EPSN);
        const float kq = QSCALE * rq * rk * sqk;          // dot(q_n, k_n)
        const float av = a_in[b * HVn + h] + dt_bias[h];
        const float sp = (av > 20.f) ? av : log1pf(__expf(av));
        const float eg = __expf(-__expf(A_log[h]) * sp);
        const float beta = 1.f / (1.f + __expf(-b_in[b * HVn + h]));
        bkq = beta * kq;
        wv[t] = eg * (rq * QSCALE * xq - bkq * rk * xk);
    }
    __syncthreads();

    // phase B: stream the 128x128 state, one dot(S[row], w) per row.
    // 16-lane groups cover one 512B row; thread owns 8 contiguous cols.
    const float4 w0 = *reinterpret_cast<const float4*>(&wv[colg * 8]);
    const float4 w1 = *reinterpret_cast<const float4*>(&wv[colg * 8 + 4]);

    // consume the 2 pre-loaded chunks
    {
        float p = e00.x * w0.x + e00.y * w0.y + e00.z * w0.z + e00.w * w0.w
                + e01.x * w1.x + e01.y * w1.y + e01.z * w1.z + e01.w * w1.w;
        p += __shfl_xor(p, 8); p += __shfl_xor(p, 4);
        p += __shfl_xor(p, 2); p += __shfl_xor(p, 1);
        if (colg == 0) po[0 * 16 + rb] = p;
        p = e10.x * w0.x + e10.y * w0.y + e10.z * w0.z + e10.w * w0.w
          + e11.x * w1.x + e11.y * w1.y + e11.z * w1.z + e11.w * w1.w;
        p += __shfl_xor(p, 8); p += __shfl_xor(p, 4);
        p += __shfl_xor(p, 2); p += __shfl_xor(p, 1);
        if (colg == 0) po[1 * 16 + rb] = p;
    }

    #pragma unroll
    for (int c = 2; c < 8; ++c) {
        const int row = c * 16 + rb;
        const float* Sr = S + (size_t)row * DDn + colg * 8;
        vf4 s0 = __builtin_nontemporal_load(reinterpret_cast<const vf4*>(Sr));
        vf4 s1 = __builtin_nontemporal_load(reinterpret_cast<const vf4*>(Sr + 4));
        float p = s0.x * w0.x + s0.y * w0.y + s0.z * w0.z + s0.w * w0.w
                + s1.x * w1.x + s1.y * w1.y + s1.z * w1.z + s1.w * w1.w;
        p += __shfl_xor(p, 8);
        p += __shfl_xor(p, 4);
        p += __shfl_xor(p, 2);
        p += __shfl_xor(p, 1);
        if (colg == 0) po[row] = p;
    }
    __syncthreads();

    if (t < DDn)
        out[(size_t)bh * DDn + t] = po[t] + bkq * vb[t];
}

extern "C" void kernel_launch(void* const* d_in, const int* in_sizes, int n_in,
                              void* d_out, int out_size, void* d_ws, size_t ws_size,
                              hipStream_t stream) {
    const float* mixed_qkv    = (const float*)d_in[0];
    const float* a_in         = (const float*)d_in[1];
    const float* b_in         = (const float*)d_in[2];
    const float* conv_state   = (const float*)d_in[3];
    const float* ssm_state    = (const float*)d_in[4];
    const float* conv_weights = (const float*)d_in[5];
    const float* dt_bias      = (const float*)d_in[6];
    const float* A_log        = (const float*)d_in[7];
    float* out = (float*)d_out;

    const int B = in_sizes[1] / HVn;   // a: (B, HV)

    fused_gdn_decode<<<B * HVn, 256, 0, stream>>>(
        mixed_qkv, a_in, b_in, conv_state, ssm_state,
        conv_weights, dt_bias, A_log, out);
}

// Round 6
// 48.294 us; speedup vs baseline: 1.1515x; 1.1515x over previous
//
#include <hip/hip_runtime.h>
#include <math.h>

#define HKn 16
#define HVn 32
#define DDn 128
#define CCn 8192          // D*(2*HK+HV)
#define EPSN 1e-6f
#define QSCALE 0.08838834764831845f   // 1/sqrt(128)

// One block per (b, h_v). Fully fused single pass:
//   out[row] = sum_c S[row][c] * w[c] + beta*kq * v[row]
//   w[c] = eg*(q_n[c]*scale - beta*kq*k_n[c])
// Plain cacheable loads (256MB state ~ L3-resident across graph replays;
// nontemporal hints measured -13% in R4). First 2 row-chunks are loaded
// into registers BEFORE the phase-A sync to hide the conv/exp chain.
__global__ __launch_bounds__(256) void fused_gdn_decode(
    const float* __restrict__ mixed_qkv,
    const float* __restrict__ a_in,
    const float* __restrict__ b_in,
    const float* __restrict__ conv_state,
    const float* __restrict__ ssm_state,
    const float* __restrict__ conv_weights,
    const float* __restrict__ dt_bias,
    const float* __restrict__ A_log,
    float* __restrict__ out)
{
    const int bh = blockIdx.x;     // b*HV + h
    const int b  = bh >> 5;
    const int h  = bh & 31;
    const int qh = h >> 1;         // rep = HV/HK = 2
    const int t  = threadIdx.x;

    __shared__ float wv[DDn];      // combined weight vector (cols)
    __shared__ float vb[DDn];      // silu'd v
    __shared__ float po[DDn];      // per-row dot results
    __shared__ float red[6];       // 2 waves x {sum q^2, sum k^2, sum q*k}

    const float* cs = conv_state + (size_t)b * 3 * CCn;
    const float* mq = mixed_qkv  + (size_t)b * CCn;

    // ---- early state loads (independent of phase A, plain cacheable) ----
    const int colg = t & 15;
    const int rb   = t >> 4;           // 0..15
    const float* S = ssm_state + (size_t)bh * DDn * DDn;
    const float* Sr0 = S + (size_t)(0 * 16 + rb) * DDn + colg * 8;
    const float* Sr1 = S + (size_t)(1 * 16 + rb) * DDn + colg * 8;
    float4 e00 = *reinterpret_cast<const float4*>(Sr0);
    float4 e01 = *reinterpret_cast<const float4*>(Sr0 + 4);
    float4 e10 = *reinterpret_cast<const float4*>(Sr1);
    float4 e11 = *reinterpret_cast<const float4*>(Sr1 + 4);

    float xq = 0.f, xk = 0.f, bkq = 0.f;

    if (t < DDn) {
        // conv + silu for q-channel and k-channel
        const int cq = qh * DDn + t;
        const int ck = (HKn + qh) * DDn + t;
        float4 w = *reinterpret_cast<const float4*>(conv_weights + (size_t)cq * 4);
        float x = cs[cq] * w.x + cs[CCn + cq] * w.y + cs[2 * CCn + cq] * w.z + mq[cq] * w.w;
        xq = x / (1.f + __expf(-x));
        w = *reinterpret_cast<const float4*>(conv_weights + (size_t)ck * 4);
        x = cs[ck] * w.x + cs[CCn + ck] * w.y + cs[2 * CCn + ck] * w.z + mq[ck] * w.w;
        xk = x / (1.f + __expf(-x));

        float sqq = xq * xq, skk = xk * xk, sqk = xq * xk;
        #pragma unroll
        for (int m = 1; m <= 32; m <<= 1) {
            sqq += __shfl_xor(sqq, m);
            skk += __shfl_xor(skk, m);
            sqk += __shfl_xor(sqk, m);
        }
        if ((t & 63) == 0) {
            const int wv_ = t >> 6;
            red[wv_ * 3 + 0] = sqq;
            red[wv_ * 3 + 1] = skk;
            red[wv_ * 3 + 2] = sqk;
        }
    } else {
        // conv + silu for v-channel
        const int cv = (2 * HKn + h) * DDn + (t - DDn);
        float4 w = *reinterpret_cast<const float4*>(conv_weights + (size_t)cv * 4);
        float x = cs[cv] * w.x + cs[CCn + cv] * w.y + cs[2 * CCn + cv] * w.z + mq[cv] * w.w;
        vb[t - DDn] = x / (1.f + __expf(-x));
    }
    __syncthreads();

    if (t < DDn) {
        const float sqq = red[0] + red[3];
        const float skk = red[1] + red[4];
        const float sqk = red[2] + red[5];
        const float rq = rsqrtf(sqq + EPSN);
        const float rk = rsqrtf(skk + EPSN);
        const float kq = QSCALE * rq * rk * sqk;          // dot(q_n, k_n)
        const float av = a_in[b * HVn + h] + dt_bias[h];
        const float sp = (av > 20.f) ? av : log1pf(__expf(av));
        const float eg = __expf(-__expf(A_log[h]) * sp);
        const float beta = 1.f / (1.f + __expf(-b_in[b * HVn + h]));
        bkq = beta * kq;
        wv[t] = eg * (rq * QSCALE * xq - bkq * rk * xk);
    }
    __syncthreads();

    // phase B: stream the 128x128 state, one dot(S[row], w) per row.
    // 16-lane groups cover one 512B row; thread owns 8 contiguous cols.
    const float4 w0 = *reinterpret_cast<const float4*>(&wv[colg * 8]);
    const float4 w1 = *reinterpret_cast<const float4*>(&wv[colg * 8 + 4]);

    // consume the 2 pre-loaded chunks
    {
        float p = e00.x * w0.x + e00.y * w0.y + e00.z * w0.z + e00.w * w0.w
                + e01.x * w1.x + e01.y * w1.y + e01.z * w1.z + e01.w * w1.w;
        p += __shfl_xor(p, 8); p += __shfl_xor(p, 4);
        p += __shfl_xor(p, 2); p += __shfl_xor(p, 1);
        if (colg == 0) po[0 * 16 + rb] = p;
        p = e10.x * w0.x + e10.y * w0.y + e10.z * w0.z + e10.w * w0.w
          + e11.x * w1.x + e11.y * w1.y + e11.z * w1.z + e11.w * w1.w;
        p += __shfl_xor(p, 8); p += __shfl_xor(p, 4);
        p += __shfl_xor(p, 2); p += __shfl_xor(p, 1);
        if (colg == 0) po[1 * 16 + rb] = p;
    }

    #pragma unroll
    for (int c = 2; c < 8; ++c) {
        const int row = c * 16 + rb;
        const float* Sr = S + (size_t)row * DDn + colg * 8;
        float4 s0 = *reinterpret_cast<const float4*>(Sr);
        float4 s1 = *reinterpret_cast<const float4*>(Sr + 4);
        float p = s0.x * w0.x + s0.y * w0.y + s0.z * w0.z + s0.w * w0.w
                + s1.x * w1.x + s1.y * w1.y + s1.z * w1.z + s1.w * w1.w;
        p += __shfl_xor(p, 8);
        p += __shfl_xor(p, 4);
        p += __shfl_xor(p, 2);
        p += __shfl_xor(p, 1);
        if (colg == 0) po[row] = p;
    }
    __syncthreads();

    if (t < DDn)
        out[(size_t)bh * DDn + t] = po[t] + bkq * vb[t];
}

extern "C" void kernel_launch(void* const* d_in, const int* in_sizes, int n_in,
                              void* d_out, int out_size, void* d_ws, size_t ws_size,
                              hipStream_t stream) {
    const float* mixed_qkv    = (const float*)d_in[0];
    const float* a_in         = (const float*)d_in[1];
    const float* b_in         = (const float*)d_in[2];
    const float* conv_state   = (const float*)d_in[3];
    const float* ssm_state    = (const float*)d_in[4];
    const float* conv_weights = (const float*)d_in[5];
    const float* dt_bias      = (const float*)d_in[6];
    const float* A_log        = (const float*)d_in[7];
    float* out = (float*)d_out;

    const int B = in_sizes[1] / HVn;   // a: (B, HV)

    fused_gdn_decode<<<B * HVn, 256, 0, stream>>>(
        mixed_qkv, a_in, b_in, conv_state, ssm_state,
        conv_weights, dt_bias, A_log, out);
}

// Round 7
// 48.187 us; speedup vs baseline: 1.1540x; 1.0022x over previous
//
#include <hip/hip_runtime.h>
#include <math.h>

#define HKn 16
#define HVn 32
#define DDn 128
#define CCn 8192          // D*(2*HK+HV)
#define EPSN 1e-6f
#define QSCALE 0.08838834764831845f   // 1/sqrt(128)

// One block per (b, h_v). Fully fused single pass:
//   out[row] = sum_c S[row][c] * w[c] + beta*kq * v[row]
//   w[c] = eg*(q_n[c]*scale - beta*kq*k_n[c])
// Load layout: 16-lane group covers a row; load1 = cols [colg*4,+4)
// (contiguous 256B across group), load2 = cols [64+colg*4,+4).
// Each vmem instruction maps to fully-consumed 128B lines (8 lines/KB,
// vs 16 for the interleaved layout) — halves TA/TCP line requests.
__global__ __launch_bounds__(256) void fused_gdn_decode(
    const float* __restrict__ mixed_qkv,
    const float* __restrict__ a_in,
    const float* __restrict__ b_in,
    const float* __restrict__ conv_state,
    const float* __restrict__ ssm_state,
    const float* __restrict__ conv_weights,
    const float* __restrict__ dt_bias,
    const float* __restrict__ A_log,
    float* __restrict__ out)
{
    const int bh = blockIdx.x;     // b*HV + h
    const int b  = bh >> 5;
    const int h  = bh & 31;
    const int qh = h >> 1;         // rep = HV/HK = 2
    const int t  = threadIdx.x;

    __shared__ float wv[DDn];      // combined weight vector (cols)
    __shared__ float vb[DDn];      // silu'd v
    __shared__ float po[DDn];      // per-row dot results
    __shared__ float red[6];       // 2 waves x {sum q^2, sum k^2, sum q*k}

    const float* cs = conv_state + (size_t)b * 3 * CCn;
    const float* mq = mixed_qkv  + (size_t)b * CCn;

    // ---- early state loads (independent of phase A, plain cacheable) ----
    const int colg = t & 15;
    const int rb   = t >> 4;           // 0..15
    const float* S = ssm_state + (size_t)bh * DDn * DDn;
    const float* Sr0 = S + (size_t)(0 * 16 + rb) * DDn;
    const float* Sr1 = S + (size_t)(1 * 16 + rb) * DDn;
    float4 e00 = *reinterpret_cast<const float4*>(Sr0 + colg * 4);
    float4 e01 = *reinterpret_cast<const float4*>(Sr0 + 64 + colg * 4);
    float4 e10 = *reinterpret_cast<const float4*>(Sr1 + colg * 4);
    float4 e11 = *reinterpret_cast<const float4*>(Sr1 + 64 + colg * 4);

    float xq = 0.f, xk = 0.f, bkq = 0.f;

    if (t < DDn) {
        // conv + silu for q-channel and k-channel
        const int cq = qh * DDn + t;
        const int ck = (HKn + qh) * DDn + t;
        float4 w = *reinterpret_cast<const float4*>(conv_weights + (size_t)cq * 4);
        float x = cs[cq] * w.x + cs[CCn + cq] * w.y + cs[2 * CCn + cq] * w.z + mq[cq] * w.w;
        xq = x / (1.f + __expf(-x));
        w = *reinterpret_cast<const float4*>(conv_weights + (size_t)ck * 4);
        x = cs[ck] * w.x + cs[CCn + ck] * w.y + cs[2 * CCn + ck] * w.z + mq[ck] * w.w;
        xk = x / (1.f + __expf(-x));

        float sqq = xq * xq, skk = xk * xk, sqk = xq * xk;
        #pragma unroll
        for (int m = 1; m <= 32; m <<= 1) {
            sqq += __shfl_xor(sqq, m);
            skk += __shfl_xor(skk, m);
            sqk += __shfl_xor(sqk, m);
        }
        if ((t & 63) == 0) {
            const int wv_ = t >> 6;
            red[wv_ * 3 + 0] = sqq;
            red[wv_ * 3 + 1] = skk;
            red[wv_ * 3 + 2] = sqk;
        }
    } else {
        // conv + silu for v-channel
        const int cv = (2 * HKn + h) * DDn + (t - DDn);
        float4 w = *reinterpret_cast<const float4*>(conv_weights + (size_t)cv * 4);
        float x = cs[cv] * w.x + cs[CCn + cv] * w.y + cs[2 * CCn + cv] * w.z + mq[cv] * w.w;
        vb[t - DDn] = x / (1.f + __expf(-x));
    }
    __syncthreads();

    if (t < DDn) {
        const float sqq = red[0] + red[3];
        const float skk = red[1] + red[4];
        const float sqk = red[2] + red[5];
        const float rq = rsqrtf(sqq + EPSN);
        const float rk = rsqrtf(skk + EPSN);
        const float kq = QSCALE * rq * rk * sqk;          // dot(q_n, k_n)
        const float av = a_in[b * HVn + h] + dt_bias[h];
        const float sp = (av > 20.f) ? av : log1pf(__expf(av));
        const float eg = __expf(-__expf(A_log[h]) * sp);
        const float beta = 1.f / (1.f + __expf(-b_in[b * HVn + h]));
        bkq = beta * kq;
        wv[t] = eg * (rq * QSCALE * xq - bkq * rk * xk);
    }
    __syncthreads();

    // phase B: stream the 128x128 state, one dot(S[row], w) per row.
    const float4 w0 = *reinterpret_cast<const float4*>(&wv[colg * 4]);
    const float4 w1 = *reinterpret_cast<const float4*>(&wv[64 + colg * 4]);

    // consume the 2 pre-loaded chunks
    {
        float p = e00.x * w0.x + e00.y * w0.y + e00.z * w0.z + e00.w * w0.w
                + e01.x * w1.x + e01.y * w1.y + e01.z * w1.z + e01.w * w1.w;
        p += __shfl_xor(p, 8); p += __shfl_xor(p, 4);
        p += __shfl_xor(p, 2); p += __shfl_xor(p, 1);
        if (colg == 0) po[0 * 16 + rb] = p;
        p = e10.x * w0.x + e10.y * w0.y + e10.z * w0.z + e10.w * w0.w
          + e11.x * w1.x + e11.y * w1.y + e11.z * w1.z + e11.w * w1.w;
        p += __shfl_xor(p, 8); p += __shfl_xor(p, 4);
        p += __shfl_xor(p, 2); p += __shfl_xor(p, 1);
        if (colg == 0) po[1 * 16 + rb] = p;
    }

    #pragma unroll
    for (int c = 2; c < 8; ++c) {
        const int row = c * 16 + rb;
        const float* Sr = S + (size_t)row * DDn;
        float4 s0 = *reinterpret_cast<const float4*>(Sr + colg * 4);
        float4 s1 = *reinterpret_cast<const float4*>(Sr + 64 + colg * 4);
        float p = s0.x * w0.x + s0.y * w0.y + s0.z * w0.z + s0.w * w0.w
                + s1.x * w1.x + s1.y * w1.y + s1.z * w1.z + s1.w * w1.w;
        p += __shfl_xor(p, 8);
        p += __shfl_xor(p, 4);
        p += __shfl_xor(p, 2);
        p += __shfl_xor(p, 1);
        if (colg == 0) po[row] = p;
    }
    __syncthreads();

    if (t < DDn)
        out[(size_t)bh * DDn + t] = po[t] + bkq * vb[t];
}

extern "C" void kernel_launch(void* const* d_in, const int* in_sizes, int n_in,
                              void* d_out, int out_size, void* d_ws, size_t ws_size,
                              hipStream_t stream) {
    const float* mixed_qkv    = (const float*)d_in[0];
    const float* a_in         = (const float*)d_in[1];
    const float* b_in         = (const float*)d_in[2];
    const float* conv_state   = (const float*)d_in[3];
    const float* ssm_state    = (const float*)d_in[4];
    const float* conv_weights = (const float*)d_in[5];
    const float* dt_bias      = (const float*)d_in[6];
    const float* A_log        = (const float*)d_in[7];
    float* out = (float*)d_out;

    const int B = in_sizes[1] / HVn;   // a: (B, HV)

    fused_gdn_decode<<<B * HVn, 256, 0, stream>>>(
        mixed_qkv, a_in, b_in, conv_state, ssm_state,
        conv_weights, dt_bias, A_log, out);
}